// Round 1
// baseline (2265.357 us; speedup 1.0000x reference)
//
#include <hip/hip_runtime.h>

#define TPB 256
static constexpr unsigned HASH_MASK = (1u << 19) - 1u;
// log(log(1/0.99)) - log(4.0) - 0.5
static constexpr float OFFSETC = -6.4864435477f;

__global__ void density_field_kernel(
    const float* __restrict__ xyz,
    const float* __restrict__ delta,
    const float* __restrict__ table,
    const float* __restrict__ w_in,
    const float* __restrict__ w_out,
    const float* __restrict__ rgb_w1,
    const float* __restrict__ rgb_w2,
    const float* __restrict__ rgb_w3,
    float* __restrict__ out)
{
    __shared__ float s_w_inT[64 * 32];   // [j][i]  (w_in is (32,64))
    __shared__ float s_w_out[64 * 16];   // [j][k]  (as-is, (64,16))
    __shared__ float s_rgb_w1T[64 * 16]; // [j][i], padded 15->16 with 0
    __shared__ float s_rgb_w2[64 * 64];  // [j][k]  (as-is)
    __shared__ float s_rgb_w3T[3 * 64];  // [k][j]  (rgb_w3 is (64,3))
    __shared__ float s_wavetot[4];

    const int tid = threadIdx.x;

    // ---- stage weights into LDS (one-time) ----
    for (int i = tid; i < 32 * 64; i += TPB) { int r = i >> 6, c = i & 63; s_w_inT[c * 32 + r] = w_in[i]; }
    for (int i = tid; i < 64 * 16; i += TPB) s_w_out[i] = w_out[i];
    for (int i = tid; i < 64 * 16; i += TPB) { int j = i >> 4, k = i & 15; s_rgb_w1T[i] = (k < 15) ? rgb_w1[k * 64 + j] : 0.f; }
    for (int i = tid; i < 64 * 64; i += TPB) s_rgb_w2[i] = rgb_w2[i];
    for (int i = tid; i < 3 * 64; i += TPB) { int k = i >> 6, j = i & 63; s_rgb_w3T[i] = rgb_w3[j * 3 + k]; }
    __syncthreads();

    const int p = blockIdx.x * TPB + tid;       // global sample index
    const float x = xyz[3 * p + 0];
    const float y = xyz[3 * p + 1];
    const float z = xyz[3 * p + 2];

    const float RES[16] = {16.f, 23.f, 33.f, 48.f, 70.f, 101.f, 147.f, 212.f,
                           307.f, 445.f, 645.f, 933.f, 1351.f, 1955.f, 2830.f, 4096.f};

    // ---- hash-grid encode: 16 levels x 2 feats ----
    float enc[32];
    #pragma unroll
    for (int l = 0; l < 16; ++l) {
        const float res = RES[l];
        const float px = x * res, py = y * res, pz = z * res;
        const float fx0 = floorf(px), fy0 = floorf(py), fz0 = floorf(pz);
        const float fx = px - fx0, fy = py - fy0, fz = pz - fz0;
        const unsigned ix = (unsigned)fx0, iy = (unsigned)fy0, iz = (unsigned)fz0;
        const unsigned hx0 = ix,                 hx1 = ix + 1u;
        const unsigned hy0 = iy * 2654435761u,   hy1 = hy0 + 2654435761u;
        const unsigned hz0 = iz * 805459861u,    hz1 = hz0 + 805459861u;
        const float2* tab = (const float2*)table + ((size_t)l << 19);
        const float2 t000 = tab[(hx0 ^ hy0 ^ hz0) & HASH_MASK];
        const float2 t001 = tab[(hx0 ^ hy0 ^ hz1) & HASH_MASK];
        const float2 t010 = tab[(hx0 ^ hy1 ^ hz0) & HASH_MASK];
        const float2 t011 = tab[(hx0 ^ hy1 ^ hz1) & HASH_MASK];
        const float2 t100 = tab[(hx1 ^ hy0 ^ hz0) & HASH_MASK];
        const float2 t101 = tab[(hx1 ^ hy0 ^ hz1) & HASH_MASK];
        const float2 t110 = tab[(hx1 ^ hy1 ^ hz0) & HASH_MASK];
        const float2 t111 = tab[(hx1 ^ hy1 ^ hz1) & HASH_MASK];
        const float gx = 1.f - fx, gy = 1.f - fy, gz = 1.f - fz;
        const float w000 = gx * gy * gz, w001 = gx * gy * fz;
        const float w010 = gx * fy * gz, w011 = gx * fy * fz;
        const float w100 = fx * gy * gz, w101 = fx * gy * fz;
        const float w110 = fx * fy * gz, w111 = fx * fy * fz;
        float a0 = w000 * t000.x; float a1 = w000 * t000.y;
        a0 += w001 * t001.x; a1 += w001 * t001.y;
        a0 += w010 * t010.x; a1 += w010 * t010.y;
        a0 += w011 * t011.x; a1 += w011 * t011.y;
        a0 += w100 * t100.x; a1 += w100 * t100.y;
        a0 += w101 * t101.x; a1 += w101 * t101.y;
        a0 += w110 * t110.x; a1 += w110 * t110.y;
        a0 += w111 * t111.x; a1 += w111 * t111.y;
        enc[2 * l + 0] = a0;
        enc[2 * l + 1] = a1;
    }

    // ---- layer1 (32->64, relu) fused with layer2 (64->16): h never stored ----
    float raw[16];
    #pragma unroll
    for (int k = 0; k < 16; ++k) raw[k] = 0.f;
    #pragma unroll
    for (int j = 0; j < 64; ++j) {
        const float4* wr = (const float4*)&s_w_inT[j * 32];
        float acc = 0.f;
        #pragma unroll
        for (int i = 0; i < 8; ++i) {
            const float4 w4 = wr[i];
            acc += w4.x * enc[4 * i + 0] + w4.y * enc[4 * i + 1]
                 + w4.z * enc[4 * i + 2] + w4.w * enc[4 * i + 3];
        }
        const float hj = fmaxf(acc, 0.f);
        const float4* wo = (const float4*)&s_w_out[j * 16];
        #pragma unroll
        for (int k = 0; k < 4; ++k) {
            const float4 w4 = wo[k];
            raw[4 * k + 0] += hj * w4.x;
            raw[4 * k + 1] += hj * w4.y;
            raw[4 * k + 2] += hj * w4.z;
            raw[4 * k + 3] += hj * w4.w;
        }
    }

    // ---- volume-rendering weights: per-ray exclusive scan over S=128 ----
    const float dlt = delta[p];
    const float dd = expf(raw[0] + OFFSETC + logf(dlt)); // density * delta
    float v = dd;
    const int lane = tid & 63;
    #pragma unroll
    for (int d = 1; d < 64; d <<= 1) {
        const float n = __shfl_up(v, d, 64);
        if (lane >= d) v += n;
    }
    const int wv = tid >> 6; // wave index in block (0..3); waves {0,1}=ray0, {2,3}=ray1
    if (lane == 63) s_wavetot[wv] = v;
    __syncthreads();
    const float prev = (wv & 1) ? s_wavetot[wv - 1] : 0.f;
    const float excl = v - dd + prev;                 // sum of dd over samples before this one
    const float wgt = (1.f - expf(-dd)) * expf(-excl);

    // ---- rgb MLP: feats(15)->64 relu ->64 relu ->3 sigmoid ----
    float f2[16];
    #pragma unroll
    for (int i = 0; i < 15; ++i) f2[i] = raw[i + 1];
    f2[15] = 0.f;

    float h2a[64];
    #pragma unroll
    for (int k = 0; k < 64; ++k) h2a[k] = 0.f;
    #pragma unroll
    for (int j = 0; j < 64; ++j) {
        const float4* w1 = (const float4*)&s_rgb_w1T[j * 16];
        float acc = 0.f;
        #pragma unroll
        for (int i = 0; i < 4; ++i) {
            const float4 w4 = w1[i];
            acc += w4.x * f2[4 * i + 0] + w4.y * f2[4 * i + 1]
                 + w4.z * f2[4 * i + 2] + w4.w * f2[4 * i + 3];
        }
        const float h1j = fmaxf(acc, 0.f);
        const float4* w2 = (const float4*)&s_rgb_w2[j * 64];
        #pragma unroll
        for (int q = 0; q < 16; ++q) {
            const float4 w4 = w2[q];
            h2a[4 * q + 0] += h1j * w4.x;
            h2a[4 * q + 1] += h1j * w4.y;
            h2a[4 * q + 2] += h1j * w4.z;
            h2a[4 * q + 3] += h1j * w4.w;
        }
    }
    float r0 = 0.f, r1 = 0.f, r2 = 0.f;
    #pragma unroll
    for (int j = 0; j < 64; ++j) {
        const float h2j = fmaxf(h2a[j], 0.f);
        r0 += h2j * s_rgb_w3T[0 * 64 + j];
        r1 += h2j * s_rgb_w3T[1 * 64 + j];
        r2 += h2j * s_rgb_w3T[2 * 64 + j];
    }
    const float s0 = 1.f / (1.f + expf(-r0));
    const float s1 = 1.f / (1.f + expf(-r1));
    const float s2 = 1.f / (1.f + expf(-r2));

    float4 o;
    o.x = wgt; o.y = s0; o.z = s1; o.w = s2;
    ((float4*)out)[p] = o;
}

extern "C" void kernel_launch(void* const* d_in, const int* in_sizes, int n_in,
                              void* d_out, int out_size, void* d_ws, size_t ws_size,
                              hipStream_t stream) {
    const float* xyz    = (const float*)d_in[0];
    const float* delta  = (const float*)d_in[1];
    const float* table  = (const float*)d_in[2];
    const float* w_in   = (const float*)d_in[3];
    const float* w_out  = (const float*)d_in[4];
    const float* rgb_w1 = (const float*)d_in[5];
    const float* rgb_w2 = (const float*)d_in[6];
    const float* rgb_w3 = (const float*)d_in[7];
    float* outp = (float*)d_out;

    const int n_points = 4096 * 128;
    density_field_kernel<<<n_points / TPB, TPB, 0, stream>>>(
        xyz, delta, table, w_in, w_out, rgb_w1, rgb_w2, rgb_w3, outp);
}